// Round 1
// baseline (3176.881 us; speedup 1.0000x reference)
//
#include <hip/hip_runtime.h>
#include <cstddef>

#define NE 2048
#define NX 3
#define NROWS (NE - 1)              // rows solved by back-substitution: i = 0..2046
#define BS 64                       // block size
#define NBLK ((NROWS + BS - 1) / BS) // 32 blocks (last block has 63 rows)
#define GCH 8                       // far-GEMV chunk count

// ws layout (floats): wf[3*NE] at offset 0  (wf[p][j] = w[j]*F[p][j])
//                     acc[3*NE] at offset 3*NE (running RHS accumulator)

static __device__ __forceinline__ float dy_of(const float* E) {
    return logf(E[NE - 1] / E[0]) / (float)(NE - 1);
}

__global__ void k_init(const float* __restrict__ E, const float* __restrict__ R,
                       const float* __restrict__ K, const float* __restrict__ S0,
                       const float* __restrict__ SC,
                       float* __restrict__ out, float* __restrict__ wf,
                       float* __restrict__ acc) {
    int i = blockIdx.x * blockDim.x + threadIdx.x;
    if (i >= NE) return;
    const size_t PL = (size_t)NE * NE;
    float dy = dy_of(E);
    float wlast = 0.5f * dy * E[NE - 1];
    float srcl[NX], Fl[NX];
#pragma unroll
    for (int p = 0; p < NX; ++p) srcl[p] = S0[p] / R[p * NE + NE - 1];
#pragma unroll
    for (int x = 0; x < NX; ++x) {
        float s = SC[x * NE + NE - 1];
#pragma unroll
        for (int p = 0; p < NX; ++p)
            s += K[(size_t)(x * NX + p) * PL + (size_t)(NE - 1) * NE + (NE - 1)] * srcl[p];
        Fl[x] = s / R[x * NE + NE - 1];
    }
    out[i] = E[i];  // output row 0 = E_grid
    if (i == NE - 1) {
#pragma unroll
        for (int x = 0; x < NX; ++x) {
            out[(1 + x) * NE + i] = Fl[x] > 0.f ? Fl[x] : 0.f;
            wf[x * NE + i] = wlast * Fl[x];
        }
        return;
    }
    // acc[x][i] = SC[x,i] + sum_p K[x,p,i,NE-1] * (wlast*F[p,NE-1] + srcl[p])
#pragma unroll
    for (int x = 0; x < NX; ++x) {
        float s = SC[x * NE + i];
#pragma unroll
        for (int p = 0; p < NX; ++p)
            s += K[(size_t)(x * NX + p) * PL + (size_t)i * NE + (NE - 1)] *
                 (wlast * Fl[p] + srcl[p]);
        acc[x * NE + i] = s;
    }
}

// Far contribution for block starting at i0: acc[x][i] += sum_{p, j in [jlo,jhi)} K[x,p,i,j]*wf[p][j]
__global__ __launch_bounds__(256) void k_gemv(const float* __restrict__ K,
                                              const float* __restrict__ wf,
                                              float* __restrict__ acc,
                                              int i0, int jlo, int jhi) {
    const size_t PL = (size_t)NE * NE;
    int i = i0 + blockIdx.x;
    int len = jhi - jlo;
    int per = (len + GCH - 1) / GCH;
    int lo = jlo + blockIdx.y * per;
    int hi = min(lo + per, jhi);
    float s0 = 0.f, s1 = 0.f, s2 = 0.f;
    for (int j = lo + (int)threadIdx.x; j < hi; j += 256) {
        float w0 = wf[0 * NE + j], w1 = wf[1 * NE + j], w2 = wf[2 * NE + j];
        const float* Kb = K + (size_t)i * NE + j;
        s0 += Kb[0 * PL] * w0 + Kb[1 * PL] * w1 + Kb[2 * PL] * w2;
        s1 += Kb[3 * PL] * w0 + Kb[4 * PL] * w1 + Kb[5 * PL] * w2;
        s2 += Kb[6 * PL] * w0 + Kb[7 * PL] * w1 + Kb[8 * PL] * w2;
    }
#pragma unroll
    for (int m = 32; m; m >>= 1) {
        s0 += __shfl_xor(s0, m);
        s1 += __shfl_xor(s1, m);
        s2 += __shfl_xor(s2, m);
    }
    __shared__ float red[4][3];
    int wv = threadIdx.x >> 6;
    if ((threadIdx.x & 63) == 0) { red[wv][0] = s0; red[wv][1] = s1; red[wv][2] = s2; }
    __syncthreads();
    if (threadIdx.x == 0) {
        float a0 = red[0][0] + red[1][0] + red[2][0] + red[3][0];
        float a1 = red[0][1] + red[1][1] + red[2][1] + red[3][1];
        float a2 = red[0][2] + red[1][2] + red[2][2] + red[3][2];
        atomicAdd(&acc[0 * NE + i], a0);
        atomicAdd(&acc[1 * NE + i], a1);
        atomicAdd(&acc[2 * NE + i], a2);
    }
}

// Sequential in-block back-substitution (one workgroup).
__global__ __launch_bounds__(256) void k_solve(const float* __restrict__ E,
                                               const float* __restrict__ R,
                                               const float* __restrict__ K,
                                               float* __restrict__ out,
                                               float* __restrict__ wf,
                                               const float* __restrict__ acc,
                                               int i0) {
    __shared__ float KT[9][BS][BS];  // 147456 B
    __shared__ float wfL[NX][BS];
    __shared__ float accL[NX][BS];
    __shared__ float RL[NX][BS];
    __shared__ float EL[BS];
    const size_t PL = (size_t)NE * NE;
    int tid = threadIdx.x;

    // stage K tile (zero outside valid rows/cols; column NE-1 handled in init)
    for (int t = tid; t < 9 * BS * BS; t += 256) {
        int pair = t / (BS * BS);
        int rem = t % (BS * BS);
        int ii = rem / BS, jj = rem % BS;
        int i = i0 + ii, j = i0 + jj;
        float v = 0.f;
        if (i < NROWS && j < NROWS) v = K[(size_t)pair * PL + (size_t)i * NE + j];
        KT[pair][ii][jj] = v;
    }
    for (int t = tid; t < BS; t += 256) {
        int i = i0 + t;
        EL[t] = (i < NE) ? E[i] : 1.f;
#pragma unroll
        for (int x = 0; x < NX; ++x) {
            wfL[x][t] = 0.f;
            RL[x][t] = (i < NROWS) ? R[x * NE + i] : 1.f;
            accL[x][t] = (i < NROWS) ? acc[x * NE + i] : 0.f;
        }
    }
    __syncthreads();

    if (tid < 64) {  // wave 0 only: wave-synchronous sequential solve, no barriers
        float dy = dy_of(E);
        int l = tid;
        for (int ii = BS - 1; ii >= 0; --ii) {
            if (i0 + ii >= NROWS) continue;
            float s0 = 0.f, s1 = 0.f, s2 = 0.f;
            int jj = ii + 1 + l;
            if (jj < BS) {
                float w0 = wfL[0][jj], w1 = wfL[1][jj], w2 = wfL[2][jj];
                s0 = KT[0][ii][jj] * w0 + KT[1][ii][jj] * w1 + KT[2][ii][jj] * w2;
                s1 = KT[3][ii][jj] * w0 + KT[4][ii][jj] * w1 + KT[5][ii][jj] * w2;
                s2 = KT[6][ii][jj] * w0 + KT[7][ii][jj] * w1 + KT[8][ii][jj] * w2;
            }
#pragma unroll
            for (int m = 32; m; m >>= 1) {
                s0 += __shfl_xor(s0, m);
                s1 += __shfl_xor(s1, m);
                s2 += __shfl_xor(s2, m);
            }
            if (l == 0) {
                int i = i0 + ii;
                float Ei = EL[ii];
                float h = -0.5f * dy * Ei;
                float b00 = h * KT[0][ii][ii] + RL[0][ii];
                float b01 = h * KT[1][ii][ii];
                float b02 = h * KT[2][ii][ii];
                float b10 = h * KT[3][ii][ii];
                float b11 = h * KT[4][ii][ii] + RL[1][ii];
                float b12 = h * KT[5][ii][ii];
                float b20 = h * KT[6][ii][ii];
                float b21 = h * KT[7][ii][ii];
                float b22 = h * KT[8][ii][ii] + RL[2][ii];
                float a0 = accL[0][ii] + s0;
                float a1 = accL[1][ii] + s1;
                float a2 = accL[2][ii] + s2;
                // Cramer / adjugate
                float C00 = b11 * b22 - b12 * b21;
                float C01 = -(b10 * b22 - b12 * b20);
                float C02 = b10 * b21 - b11 * b20;
                float C10 = -(b01 * b22 - b02 * b21);
                float C11 = b00 * b22 - b02 * b20;
                float C12 = -(b00 * b21 - b01 * b20);
                float C20 = b01 * b12 - b02 * b11;
                float C21 = -(b00 * b12 - b02 * b10);
                float C22 = b00 * b11 - b01 * b10;
                float det = b00 * C00 + b01 * C01 + b02 * C02;
                float inv = 1.f / det;
                float F0 = (C00 * a0 + C10 * a1 + C20 * a2) * inv;
                float F1 = (C01 * a0 + C11 * a1 + C21 * a2) * inv;
                float F2 = (C02 * a0 + C12 * a1 + C22 * a2) * inv;
                float wi = dy * Ei;
                wfL[0][ii] = wi * F0;
                wfL[1][ii] = wi * F1;
                wfL[2][ii] = wi * F2;
                wf[0 * NE + i] = wi * F0;
                wf[1 * NE + i] = wi * F1;
                wf[2 * NE + i] = wi * F2;
                out[1 * NE + i] = F0 > 0.f ? F0 : 0.f;
                out[2 * NE + i] = F1 > 0.f ? F1 : 0.f;
                out[3 * NE + i] = F2 > 0.f ? F2 : 0.f;
            }
            __builtin_amdgcn_wave_barrier();  // keep LDS write->read order across iterations
        }
    }
}

extern "C" void kernel_launch(void* const* d_in, const int* in_sizes, int n_in,
                              void* d_out, int out_size, void* d_ws, size_t ws_size,
                              hipStream_t stream) {
    const float* E = (const float*)d_in[0];
    const float* R = (const float*)d_in[1];
    const float* K = (const float*)d_in[2];
    const float* S0 = (const float*)d_in[3];
    const float* SC = (const float*)d_in[4];
    float* out = (float*)d_out;
    float* wf = (float*)d_ws;
    float* acc = wf + NX * NE;

    k_init<<<(NE + 255) / 256, 256, 0, stream>>>(E, R, K, S0, SC, out, wf, acc);

    for (int b = NBLK - 1; b >= 0; --b) {
        int i0 = b * BS;
        if (b < NBLK - 1) {
            int jlo = i0 + BS;
            int jhi = NROWS;
            dim3 grid(BS, GCH);
            k_gemv<<<grid, 256, 0, stream>>>(K, wf, acc, i0, jlo, jhi);
        }
        k_solve<<<1, 256, 0, stream>>>(E, R, K, out, wf, acc, i0);
    }
}

// Round 2
// 606.541 us; speedup vs baseline: 5.2377x; 5.2377x over previous
//
#include <hip/hip_runtime.h>
#include <cstddef>

#define NE 2048
#define NX 3
#define NROWS (NE - 1)               // rows solved by back-substitution: i = 0..2046
#define BS 64                        // block size (rows per block)
#define BR (3 * BS)                  // 192: rows of the per-block linear operator
#define NBLK ((NROWS + BS - 1) / BS) // 32 blocks
#define GCH 8                        // far-GEMV chunk count

// ws layout (floats):
//   wf  [3*NE]           @ 0        wf[p][j] = w[j]*F[p][j]
//   acc [3*NE]           @ 3*NE     running RHS accumulator
//   G   [NBLK*BR*BR]     @ 6*NE     per-block T^{-1}, row-major within block
// total = 12288 + 32*36864 floats = 4.77 MB

static __device__ __forceinline__ float dy_of(const float* E) {
    return logf(E[NE - 1] / E[0]) / (float)(NE - 1);
}

__global__ void k_init(const float* __restrict__ E, const float* __restrict__ R,
                       const float* __restrict__ K, const float* __restrict__ S0,
                       const float* __restrict__ SC,
                       float* __restrict__ out, float* __restrict__ wf,
                       float* __restrict__ acc) {
    int i = blockIdx.x * blockDim.x + threadIdx.x;
    if (i >= NE) return;
    const size_t PL = (size_t)NE * NE;
    float dy = dy_of(E);
    float wlast = 0.5f * dy * E[NE - 1];
    float srcl[NX], Fl[NX];
#pragma unroll
    for (int p = 0; p < NX; ++p) srcl[p] = S0[p] / R[p * NE + NE - 1];
#pragma unroll
    for (int x = 0; x < NX; ++x) {
        float s = SC[x * NE + NE - 1];
#pragma unroll
        for (int p = 0; p < NX; ++p)
            s += K[(size_t)(x * NX + p) * PL + (size_t)(NE - 1) * NE + (NE - 1)] * srcl[p];
        Fl[x] = s / R[x * NE + NE - 1];
    }
    out[i] = E[i];  // output row 0 = E_grid
    if (i == NE - 1) {
#pragma unroll
        for (int x = 0; x < NX; ++x) {
            out[(1 + x) * NE + i] = Fl[x] > 0.f ? Fl[x] : 0.f;
            wf[x * NE + i] = wlast * Fl[x];
            acc[x * NE + i] = 0.f;  // keep matvec reads of the pad column finite/zero
        }
        return;
    }
    // acc[x][i] = SC[x,i] + sum_p K[x,p,i,NE-1] * (wlast*F[p,NE-1] + srcl[p])
#pragma unroll
    for (int x = 0; x < NX; ++x) {
        float s = SC[x * NE + i];
#pragma unroll
        for (int p = 0; p < NX; ++p)
            s += K[(size_t)(x * NX + p) * PL + (size_t)i * NE + (NE - 1)] *
                 (wlast * Fl[p] + srcl[p]);
        acc[x * NE + i] = s;
    }
}

// Precompute per-block inverse of the in-block operator T (block-upper-triangular,
// 3x3 blocks): T_ii = B_i = -0.5*dy*E_i*K[:,:,i,i] + diag(R[:,i]);
// T_ij = -K[:,:,i,j]*w_j (j>i, w_j = dy*E_j).  X = T^{-1}, computed column-parallel:
// for ii = 63..0:  X[3ii+r][col] = Binv_ii @ ( e + sum_{jj>ii} M_{ii,jj} X[3jj][col] ).
__global__ __launch_bounds__(256) void k_tinv(const float* __restrict__ E,
                                              const float* __restrict__ R,
                                              const float* __restrict__ K,
                                              float* __restrict__ G) {
    __shared__ float X[BR][BR];      // 147456 B
    __shared__ float Binv[BS][9];    // 2304 B
    __shared__ float Krow[9 * BS];   // 2304 B  (current step's K row-block)
    __shared__ float wloc[BS];
    const size_t PL = (size_t)NE * NE;
    int b = blockIdx.x;
    int i0 = b * BS;
    int tid = threadIdx.x;
    float dy = dy_of(E);

    for (int t = tid; t < BS; t += 256) {
        int j = i0 + t;
        wloc[t] = (j < NE - 1) ? dy * E[j] : 0.f;
    }
    if (tid < BS) {
        int ii = tid, i = i0 + ii;
        float b00, b01, b02, b10, b11, b12, b20, b21, b22;
        if (i < NROWS) {
            float h = -0.5f * dy * E[i];
            size_t d = (size_t)i * NE + i;
            b00 = h * K[0 * PL + d] + R[0 * NE + i];
            b01 = h * K[1 * PL + d];
            b02 = h * K[2 * PL + d];
            b10 = h * K[3 * PL + d];
            b11 = h * K[4 * PL + d] + R[1 * NE + i];
            b12 = h * K[5 * PL + d];
            b20 = h * K[6 * PL + d];
            b21 = h * K[7 * PL + d];
            b22 = h * K[8 * PL + d] + R[2 * NE + i];
        } else {
            b00 = 1.f; b01 = 0.f; b02 = 0.f;
            b10 = 0.f; b11 = 1.f; b12 = 0.f;
            b20 = 0.f; b21 = 0.f; b22 = 1.f;
        }
        float C00 = b11 * b22 - b12 * b21;
        float C01 = -(b10 * b22 - b12 * b20);
        float C02 = b10 * b21 - b11 * b20;
        float C10 = -(b01 * b22 - b02 * b21);
        float C11 = b00 * b22 - b02 * b20;
        float C12 = -(b00 * b21 - b01 * b20);
        float C20 = b01 * b12 - b02 * b11;
        float C21 = -(b00 * b12 - b02 * b10);
        float C22 = b00 * b11 - b01 * b10;
        float inv = 1.f / (b00 * C00 + b01 * C01 + b02 * C02);
        // Binv row-major: Binv[r][c] = C(c,r)*inv (adjugate transpose)
        Binv[ii][0] = C00 * inv; Binv[ii][1] = C10 * inv; Binv[ii][2] = C20 * inv;
        Binv[ii][3] = C01 * inv; Binv[ii][4] = C11 * inv; Binv[ii][5] = C21 * inv;
        Binv[ii][6] = C02 * inv; Binv[ii][7] = C12 * inv; Binv[ii][8] = C22 * inv;
    }
    __syncthreads();

    for (int ii = BS - 1; ii >= 0; --ii) {
        int i = i0 + ii;
        int n = BS - 1 - ii;
        // stage this row-block of K: Krow[pair*BS + jj] for jj in (ii,64)
        for (int t = tid; t < 9 * n; t += 256) {
            int pair = t / n;
            int q = t % n;
            int jj = ii + 1 + q;
            float v = 0.f;
            if (i < NROWS) v = K[(size_t)pair * PL + (size_t)i * NE + (i0 + jj)];
            Krow[pair * BS + jj] = v;
        }
        __syncthreads();
        if (tid < BR) {
            int col = tid;
            float v0 = (col == 3 * ii + 0) ? 1.f : 0.f;
            float v1 = (col == 3 * ii + 1) ? 1.f : 0.f;
            float v2 = (col == 3 * ii + 2) ? 1.f : 0.f;
            for (int jj = ii + 1; jj < BS; ++jj) {
                float w = wloc[jj];
                float x0 = X[3 * jj + 0][col];
                float x1 = X[3 * jj + 1][col];
                float x2 = X[3 * jj + 2][col];
                v0 += w * (Krow[0 * BS + jj] * x0 + Krow[1 * BS + jj] * x1 + Krow[2 * BS + jj] * x2);
                v1 += w * (Krow[3 * BS + jj] * x0 + Krow[4 * BS + jj] * x1 + Krow[5 * BS + jj] * x2);
                v2 += w * (Krow[6 * BS + jj] * x0 + Krow[7 * BS + jj] * x1 + Krow[8 * BS + jj] * x2);
            }
            const float* bv = Binv[ii];
            X[3 * ii + 0][col] = bv[0] * v0 + bv[1] * v1 + bv[2] * v2;
            X[3 * ii + 1][col] = bv[3] * v0 + bv[4] * v1 + bv[5] * v2;
            X[3 * ii + 2][col] = bv[6] * v0 + bv[7] * v1 + bv[8] * v2;
        }
        __syncthreads();
    }

    float* Gb = G + (size_t)b * BR * BR;
    for (int t = tid; t < BR * BR; t += 256)
        Gb[t] = X[t / BR][t % BR];
}

// Far contribution: acc[x][i] += sum_{p, j in [jlo,jhi)} K[x,p,i,j]*wf[p][j]
__global__ __launch_bounds__(256) void k_gemv(const float* __restrict__ K,
                                              const float* __restrict__ wf,
                                              float* __restrict__ acc,
                                              int i0, int jlo, int jhi) {
    const size_t PL = (size_t)NE * NE;
    int i = i0 + blockIdx.x;
    int len = jhi - jlo;
    int per = (len + GCH - 1) / GCH;
    int lo = jlo + blockIdx.y * per;
    int hi = min(lo + per, jhi);
    float s0 = 0.f, s1 = 0.f, s2 = 0.f;
    for (int j = lo + (int)threadIdx.x; j < hi; j += 256) {
        float w0 = wf[0 * NE + j], w1 = wf[1 * NE + j], w2 = wf[2 * NE + j];
        const float* Kb = K + (size_t)i * NE + j;
        s0 += Kb[0 * PL] * w0 + Kb[1 * PL] * w1 + Kb[2 * PL] * w2;
        s1 += Kb[3 * PL] * w0 + Kb[4 * PL] * w1 + Kb[5 * PL] * w2;
        s2 += Kb[6 * PL] * w0 + Kb[7 * PL] * w1 + Kb[8 * PL] * w2;
    }
#pragma unroll
    for (int m = 32; m; m >>= 1) {
        s0 += __shfl_xor(s0, m);
        s1 += __shfl_xor(s1, m);
        s2 += __shfl_xor(s2, m);
    }
    __shared__ float red[4][3];
    int wv = threadIdx.x >> 6;
    if ((threadIdx.x & 63) == 0) { red[wv][0] = s0; red[wv][1] = s1; red[wv][2] = s2; }
    __syncthreads();
    if (threadIdx.x == 0) {
        float a0 = red[0][0] + red[1][0] + red[2][0] + red[3][0];
        float a1 = red[0][1] + red[1][1] + red[2][1] + red[3][1];
        float a2 = red[0][2] + red[1][2] + red[2][2] + red[3][2];
        atomicAdd(&acc[0 * NE + i], a0);
        atomicAdd(&acc[1 * NE + i], a1);
        atomicAdd(&acc[2 * NE + i], a2);
    }
}

// Apply the precomputed block inverse: F_blk = G_b @ a_blk; write out, wf.
__global__ __launch_bounds__(256) void k_apply(const float* __restrict__ E,
                                               const float* __restrict__ G,
                                               const float* __restrict__ acc,
                                               float* __restrict__ out,
                                               float* __restrict__ wf,
                                               int b) {
    __shared__ float aL[BR];
    int i0 = b * BS;
    int tid = threadIdx.x;
    if (tid < BR) {
        int jj = tid / 3, x = tid % 3;
        int i = i0 + jj;
        aL[tid] = (i < NROWS) ? acc[x * NE + i] : 0.f;
    }
    __syncthreads();
    if (tid < BR) {
        int ii = tid / 3, x = tid % 3;
        int i = i0 + ii;
        const float4* row = (const float4*)(G + (size_t)b * BR * BR + (size_t)tid * BR);
        const float4* av = (const float4*)aL;
        float s = 0.f;
#pragma unroll 8
        for (int c = 0; c < BR / 4; ++c) {
            float4 g = row[c];
            float4 a = av[c];
            s += g.x * a.x + g.y * a.y + g.z * a.z + g.w * a.w;
        }
        if (i < NROWS) {
            float dy = dy_of(E);
            out[(1 + x) * NE + i] = s > 0.f ? s : 0.f;
            wf[x * NE + i] = dy * E[i] * s;
        }
    }
}

extern "C" void kernel_launch(void* const* d_in, const int* in_sizes, int n_in,
                              void* d_out, int out_size, void* d_ws, size_t ws_size,
                              hipStream_t stream) {
    const float* E = (const float*)d_in[0];
    const float* R = (const float*)d_in[1];
    const float* K = (const float*)d_in[2];
    const float* S0 = (const float*)d_in[3];
    const float* SC = (const float*)d_in[4];
    float* out = (float*)d_out;
    float* wf = (float*)d_ws;
    float* acc = wf + NX * NE;
    float* G = acc + NX * NE;

    k_init<<<(NE + 255) / 256, 256, 0, stream>>>(E, R, K, S0, SC, out, wf, acc);
    k_tinv<<<NBLK, 256, 0, stream>>>(E, R, K, G);

    for (int b = NBLK - 1; b >= 0; --b) {
        int i0 = b * BS;
        if (b < NBLK - 1) {
            dim3 grid(BS, GCH);
            k_gemv<<<grid, 256, 0, stream>>>(K, wf, acc, i0, i0 + BS, NROWS);
        }
        k_apply<<<1, 256, 0, stream>>>(E, G, acc, out, wf, b);
    }
}